// Round 6
// baseline (56.857 us; speedup 1.0000x reference)
//
#include <hip/hip_runtime.h>

#define NSLICE 6
#define NPIX   4096
#define M      20
#define TPB    512

// K(d)=exp(-(d/sigma)^2), sigma=0.1, on d in [-1,1]:
//   K(d) ~= c0 + sum_{m=1..M} 2*c_m*cos(pi*m*d), c_m=(sigma*sqrt(pi)/2)*exp(-(pi*m*sigma)^2/4)
#define C0         0.088622693f
#define TWO_C0     0.177245385f
#define AEXP_LOG2  0.035597112f    // (pi*sigma)^2/4 * log2(e)
#define DEN0       362.99854f      // C0 * NPIX

// Single launch, 48 blocks (8 per slice). Each block REDUNDANTLY computes its
// slice's full Fourier moments (no cross-block dependency -> no second kernel,
// no graph-node gap), then recombines its own 512-pixel tile.
// Register budget: 20 moment accumulators/thread (4 fg-groups x 5 freqs via
// in-group Chebyshev recurrence) — ~45 live VGPRs, no spill (round-4 lesson).
__global__ __launch_bounds__(TPB) void bilateral_fused(
        const float* __restrict__ x, float* __restrict__ out) {
    __shared__ float4 part4[32][4][5];   // [group][fg][freq] (Sc,Ss,Tc,Ts), 10 KB
    __shared__ float  xpart[32];
    __shared__ __align__(16) float fin[(M + 1) * 4];

    const int tid = threadIdx.x;
    const int s   = blockIdx.x >> 3;     // slice
    const int bt  = blockIdx.x & 7;      // tile within slice (phase 2)
    const float* xs = x + s * NPIX;

    // ---- Phase 1: full-slice moments. fg-group handles freqs 5*fg+1..5*fg+5
    // over pixel set (tid>>2); the 4 fg threads of a set share its 32 pixels.
    const int fg  = tid & 3;
    const int set = tid >> 2;            // 128 sets x 32 px
    const float a = (float)(5 * fg);     // starter frequency (m = a)

    float Sc[5], Ss[5], Tc[5], Ts[5], X = 0.f;
    #pragma unroll
    for (int k = 0; k < 5; ++k) { Sc[k]=0.f; Ss[k]=0.f; Tc[k]=0.f; Ts[k]=0.f; }

    const float4* x4 = (const float4*)xs;
    #pragma unroll
    for (int j = 0; j < 8; ++j) {
        float4 v4 = x4[set * 8 + j];
        float vv[4] = {v4.x, v4.y, v4.z, v4.w};
        #pragma unroll
        for (int u = 0; u < 4; ++u) {
            float v = vv[u];
            X += v;
            float h  = 0.5f * v;                          // revolutions for pi*v
            float c1 = __builtin_amdgcn_cosf(h);          // cos(pi v): rec multiplier
            float tc = c1 + c1;
            float cp = __builtin_amdgcn_cosf(a * h);      // cos(pi a v)
            float sp = __builtin_amdgcn_sinf(a * h);
            float cc = __builtin_amdgcn_cosf(fmaf(a, h, h)); // cos(pi(a+1)v)
            float ss = __builtin_amdgcn_sinf(fmaf(a, h, h));
            #pragma unroll
            for (int k = 0; k < 5; ++k) {                 // freqs a+1 .. a+5
                Sc[k] += cc;  Ss[k] += ss;
                Tc[k] = fmaf(v, cc, Tc[k]);  Ts[k] = fmaf(v, ss, Ts[k]);
                float cn = fmaf(tc, cc, -cp);             // Chebyshev step
                float sn = fmaf(tc, ss, -sp);
                cp = cc; cc = cn; sp = ss; ss = sn;
            }
        }
    }

    // 2 shfl steps (fg-preserving): lane sums its 4 fg-mates within its 16-row.
    #pragma unroll
    for (int off = 4; off <= 8; off <<= 1) {
        X += __shfl_xor(X, off);
        #pragma unroll
        for (int k = 0; k < 5; ++k) {
            Sc[k] += __shfl_xor(Sc[k], off);
            Ss[k] += __shfl_xor(Ss[k], off);
            Tc[k] += __shfl_xor(Tc[k], off);
            Ts[k] += __shfl_xor(Ts[k], off);
        }
    }
    const int lane = tid & 63;
    const int wv   = tid >> 6;                    // 8 waves
    if ((lane & 12) == 0) {                       // lanes 0-3,16-19,32-35,48-51
        int g = (wv << 2) | (lane >> 4);          // 32 groups of 4 sets
        #pragma unroll
        for (int k = 0; k < 5; ++k)
            part4[g][fg][k] = make_float4(Sc[k], Ss[k], Tc[k], Ts[k]);
        if ((lane & 15) == 0) xpart[g] = X;       // fg==0 writer: X counted once
    }
    __syncthreads();

    // Final cross-group sums: 81 threads, 32 reads each. Flat-index identity:
    // value (m0 = tid>>2, kind = tid&3) lives at pf[g*80 + tid].
    if (tid < 81) {
        if (tid == 80) {
            float xx = 0.f;
            #pragma unroll
            for (int g = 0; g < 32; ++g) xx += xpart[g];
            fin[0] = DEN0;  fin[1] = C0 * xx;  fin[2] = 0.f;  fin[3] = 0.f;
        } else {
            const float* pf = (const float*)part4;
            float sum = 0.f;
            #pragma unroll
            for (int g = 0; g < 32; ++g) sum += pf[g * 80 + tid];
            int m = (tid >> 2) + 1;
            float fm = (float)m;
            float coef = TWO_C0 * __builtin_amdgcn_exp2f(-AEXP_LOG2 * fm * fm);
            fin[m * 4 + (tid & 3)] = coef * sum;
        }
    }
    __syncthreads();

    // ---- Phase 2: recombine this block's 512-pixel tile (1 px/thread).
    const int p = bt * TPB + tid;
    float v  = xs[p];
    float h  = 0.5f * v;
    float s1 = __builtin_amdgcn_sinf(h);          // sin(pi v)
    float c1 = __builtin_amdgcn_cosf(h);          // cos(pi v)
    const float4* F = (const float4*)fin;
    float4 f0 = F[0], f1 = F[1];
    float den = fmaf(c1, f1.x, f0.x);  den = fmaf(s1, f1.y, den);
    float num = fmaf(c1, f1.z, f0.y);  num = fmaf(s1, f1.w, num);
    float tc = c1 + c1, cm2 = 1.f, sm2 = 0.f, cm1 = c1, sm1 = s1;
    #pragma unroll
    for (int m = 2; m <= M; ++m) {
        float cn = fmaf(tc, cm1, -cm2);
        float sn = fmaf(tc, sm1, -sm2);
        cm2 = cm1; cm1 = cn; sm2 = sm1; sm1 = sn;
        float4 f = F[m];                           // LDS broadcast read
        den = fmaf(cn, f.x, den);  den = fmaf(sn, f.y, den);
        num = fmaf(cn, f.z, num);  num = fmaf(sn, f.w, num);
    }
    out[s * NPIX + p] = num / den;
}

extern "C" void kernel_launch(void* const* d_in, const int* in_sizes, int n_in,
                              void* d_out, int out_size, void* d_ws, size_t ws_size,
                              hipStream_t stream) {
    const float* x = (const float*)d_in[0];
    float* out = (float*)d_out;
    bilateral_fused<<<dim3(NSLICE * 8), dim3(TPB), 0, stream>>>(x, out);
}